// Round 23
// baseline (268.628 us; speedup 1.0000x reference)
//
#include <hip/hip_runtime.h>

#define NA 50000
#define NT 25000
#define EAA 800000
#define EAT 400000
#define ETA 400000
#define NSEG 125000          // NA + NA + NT rows: [aa | ta | at]
#define TOTAL_E 1600000
#define NB 489               // coarse buckets of 256 rows
#define NBLK1 391            // pass-1 blocks
#define CHUNK 4096           // edges per pass-1 block
#define CAP 6144             // REC slab capacity per bucket (max observed bucket ~4800)
#define SRCH_STRIDE 75008    // per-copy src-histogram stride: at[50000] | ta[25000] | pad

// ---- workspace layout (4-byte element offsets) ----
#define O_SRCH    0          // int[8*75008]: 8 XCD-local src-degree histogram copies
#define O_BTOT    600064     // int[512]: per-bucket totals (adjacent to SRCH -> single memset)
#define O_RO      600576     // int[125001]: CSR row offsets
#define O_CAA     725584     // float[50000]: rsqrt(indeg_aa+1)
#define O_CTAD    775584     // float[50000]
#define O_CATD    825584     // float[25000]
#define O_CATS    850584     // float[50000]
#define O_CTAS    900584     // float[25000]
#define O_U       925600     // float[512] (padded start)
#define O_P       926112     // float[100000]
#define O_Q       1026112    // float[100000]
#define O_R       1126112    // float[50000]
#define O_REC     1176112    // int[NB*CAP=3004416]: slabbed bucket-sorted records
#define O_CSR     4180528    // ushort[1600000] = 800000 ints

// ---------- fused pass 1: load edges once -> LDS bucket sort -> slab flush (+ src degrees) ----------
__global__ void __launch_bounds__(1024)
p1_fused_kernel(const int* __restrict__ src_aa, const int* __restrict__ dst_aa,
                const int* __restrict__ src_ta, const int* __restrict__ dst_ta,
                const int* __restrict__ src_at, const int* __restrict__ dst_at,
                int* __restrict__ wi) {
    __shared__ int recs[CHUNK];              // staged packed (rl<<16)|src
    __shared__ unsigned short bkt[CHUNK];    // bucket per staged edge
    __shared__ int sorted[CHUNK];            // bucket-sorted records
    __shared__ unsigned short sbkt[CHUNK];   // bucket per sorted slot
    __shared__ int cnt[NB];                  // per-bucket count
    __shared__ int cur[NB];                  // scan cursor (ends at offs+cnt)
    __shared__ int gbase[NB];                // scan buffer, then global base - offs
    int b = blockIdx.x, tid = threadIdx.x;
    int* rec_g = wi + O_REC;

    for (int i = tid; i < NB; i += 1024) cnt[i] = 0;
    __syncthreads();

    // phase A: load + stage + count (+ XCD-local src-degree atomics)
    int t0 = b * CHUNK;
    int n = min(CHUNK, TOTAL_E - t0);
    int* srch = wi + O_SRCH + (b & 7) * SRCH_STRIDE;
    for (int i = tid; i < n; i += 1024) {
        int t = t0 + i, row, s;
        if (t < EAA) {
            row = dst_aa[t]; s = src_aa[t];
        } else if (t < EAA + ETA) {
            int u = t - EAA;
            row = NA + dst_ta[u]; s = src_ta[u];
            atomicAdd(&srch[50000 + s], 1);
        } else {
            int u = t - EAA - ETA;
            row = 2 * NA + dst_at[u]; s = src_at[u];
            atomicAdd(&srch[s], 1);
        }
        int bk = row >> 8;
        recs[i] = ((row & 255) << 16) | s;
        bkt[i] = (unsigned short)bk;
        atomicAdd(&cnt[bk], 1);
    }
    __syncthreads();

    // phase B: exclusive scan of cnt -> cur (scan buffer = gbase)
    if (tid < NB) gbase[tid] = cnt[tid];
    __syncthreads();
    for (int off = 1; off < NB; off <<= 1) {
        int x = 0;
        if (tid < NB && tid >= off) x = gbase[tid - off];
        __syncthreads();
        if (tid < NB) gbase[tid] += x;
        __syncthreads();
    }
    if (tid < NB) cur[tid] = gbase[tid] - cnt[tid];   // exclusive offs
    __syncthreads();

    // phase C: place into LDS-sorted order
    for (int i = tid; i < n; i += 1024) {
        int bk = bkt[i];
        int pos = atomicAdd(&cur[bk], 1);
        sorted[pos] = recs[i];
        sbkt[pos] = (unsigned short)bk;
    }
    __syncthreads();

    // phase D: reserve global slab space per bucket; gbase = slab_base - offs
    for (int bk = tid; bk < NB; bk += 1024) {
        int len = cnt[bk];
        if (len > 0) {
            int gb = atomicAdd(&wi[O_BTOT + bk], len);
            gbase[bk] = bk * CAP + gb - (cur[bk] - len);   // cur now = offs+len
        }
    }
    __syncthreads();

    // phase E: flush contiguous runs to the slab
    for (int i = tid; i < n; i += 1024) {
        int bk = sbkt[i];
        rec_g[gbase[bk] + i] = sorted[i];
    }
}

// ---------- fused pass 2 + aux: blocks 0..NB-1 = p2 (self-computed base); NB..NB+73 = src coefs; NB+74 = U ----------
__global__ void __launch_bounds__(1024)
p2_aux_kernel(int* __restrict__ wi, float* __restrict__ wf,
              const float* __restrict__ W2_aa, const float* __restrict__ W2_ta,
              const float* __restrict__ W2_at, const float* __restrict__ b2_aa,
              const float* __restrict__ b2_ta, const float* __restrict__ b2_at,
              const float* __restrict__ Wp_a, const float* __restrict__ bp_a,
              const float* __restrict__ Wp_t, const float* __restrict__ bp_t) {
    int bb = blockIdx.x, tid = threadIdx.x, lane = tid & 63, wid = tid >> 6;
    if (bb < NB) {
        const int* rec = wi + O_REC;
        unsigned short* csr = (unsigned short*)(wi + O_CSR);
        int* ro = wi + O_RO;
        float* caa = wf + O_CAA;
        float* ctad = wf + O_CTAD;
        float* catd = wf + O_CATD;
        __shared__ int deg[256];
        __shared__ int rb[256];
        __shared__ int wsum[16];
        int k = bb;
        // self-compute g0 = sum of BTOT[0..k)
        int a = (tid < k) ? wi[O_BTOT + tid] : 0;
#pragma unroll
        for (int m = 32; m; m >>= 1) a += __shfl_xor(a, m, 64);
        if (lane == 0) wsum[wid] = a;
        if (tid < 256) deg[tid] = 0;
        __syncthreads();
        int g0 = 0;
#pragma unroll
        for (int w = 0; w < 16; ++w) g0 += wsum[w];
        int s0 = k * CAP;                       // slab base
        int len = wi[O_BTOT + k];
        for (int j = tid; j < len; j += 1024) atomicAdd(&deg[rec[s0 + j] >> 16], 1);
        __syncthreads();
        int v = 0, x = 0;
        if (tid < 256) {
            v = deg[tid];
            x = v;
#pragma unroll
            for (int off = 1; off < 64; off <<= 1) {
                int y = __shfl_up(x, off, 64);
                if (lane >= off) x += y;
            }
            if (lane == 63) wsum[wid] = x;
        }
        __syncthreads();
        if (tid < 256) {
            int wpre = 0;
            for (int w = 0; w < wid; ++w) wpre += wsum[w];
            int excl = x - v + wpre;
            rb[tid] = g0 + excl;
            int g = k * 256 + tid;
            if (g < NSEG) {
                ro[g] = g0 + excl;
                if (g < NA) caa[g] = rsqrtf((float)v + 1.0f);
                else if (g < 2 * NA) ctad[g - NA] = v > 0 ? rsqrtf((float)v) : 0.0f;
                else catd[g - 2 * NA] = v > 0 ? rsqrtf((float)v) : 0.0f;
            }
            if (k == NB - 1 && tid == 0) ro[NSEG] = TOTAL_E;
        }
        __syncthreads();
        for (int j = tid; j < len; j += 1024) {
            int rc = rec[s0 + j];
            int pos = atomicAdd(&rb[rc >> 16], 1);
            csr[pos] = (unsigned short)(rc & 0xFFFF);
        }
    } else if (bb < NB + 74) {
        int t = (bb - NB) * 1024 + tid;
        if (t < 75000) {
            int d = 0;
#pragma unroll
            for (int c = 0; c < 8; ++c) d += wi[O_SRCH + c * SRCH_STRIDE + t];
            float v = d > 0 ? rsqrtf((float)d) : 0.0f;
            if (t < 50000) wf[O_CATS + t] = v;
            else           wf[O_CTAS + (t - 50000)] = v;
        }
    } else {
        float* U = wf + O_U;
        int t = tid;
        if (t < 128) {
            int k = t >> 1, j = t & 1;
            float a = 0.f;
            for (int f = 0; f < 64; ++f) a = fmaf(W2_aa[k * 64 + f], Wp_a[f * 2 + j], a);
            U[t] = a;
        } else if (t < 256) {
            int u = t - 128; int k = u >> 1, j = u & 1;
            float a = 0.f;
            for (int f = 0; f < 64; ++f) a = fmaf(W2_ta[k * 64 + f], Wp_a[f * 2 + j], a);
            U[128 + u] = a;
        } else if (t < 384) {
            int u = t - 256; int k = u >> 1, j = u & 1;
            float a = 0.f;
            for (int f = 0; f < 64; ++f) a = fmaf(W2_at[k * 64 + f], Wp_t[f * 2 + j], a);
            U[256 + u] = a;
        } else if (t < 386) {
            int j = t - 384;
            float a = bp_a[j];
            for (int f = 0; f < 64; ++f) a = fmaf(b2_aa[f] + b2_ta[f], Wp_a[f * 2 + j], a);
            U[384 + j] = a;
        } else if (t < 388) {
            int j = t - 386;
            float a = bp_t[j];
            for (int f = 0; f < 64; ++f) a = fmaf(b2_at[f], Wp_t[f * 2 + j], a);
            U[386 + j] = a;
        }
    }
}

// ---------- conv1: preload+shfl gather + LDS-broadcast matvec (pad-33 W in LDS) ----------
__global__ void __launch_bounds__(256)
conv1_all_kernel(const float* __restrict__ x_a, const float* __restrict__ x_t,
                 const int* __restrict__ ro, const unsigned short* __restrict__ csr,
                 const float* __restrict__ c_aa, const float* __restrict__ c_ta_d,
                 const float* __restrict__ c_ta_s, const float* __restrict__ c_at_s,
                 const float* __restrict__ c_at_d,
                 const float* __restrict__ W_aa, const float* __restrict__ b_aa,
                 const float* __restrict__ W_ta, const float* __restrict__ b_ta,
                 const float* __restrict__ W_at, const float* __restrict__ b_at,
                 const float* __restrict__ U,
                 float* __restrict__ p, float* __restrict__ q, float* __restrict__ r) {
    __shared__ float sW0[64 * 33];   // transposed: sW0[col*33 + k], stride 33 -> 2-way banks (free)
    __shared__ float sW1[64 * 33];
    __shared__ float sAggA[4][32];   // per-wave reduced agg (wave-coherent, no barrier)
    __shared__ float sAggT[4][32];
    int lane = threadIdx.x & 63;
    int wave = threadIdx.x >> 6;
    int e8 = lane >> 3, k4 = lane & 7;

    if (blockIdx.x < NA / 4) {
        // ---------- agents ----------
        for (int idx = threadIdx.x; idx < 2048; idx += 256) {
            int k = idx >> 6, col = idx & 63;
            sW0[col * 33 + k] = W_aa[idx];
            sW1[col * 33 + k] = W_ta[idx];
        }
        __syncthreads();
        int i = blockIdx.x * 4 + wave;
        float ci = c_aa[i];
        float bias = b_aa[lane] + b_ta[lane];
        int b0 = ro[i], e0v = ro[i + 1];
        int b1 = ro[NA + i], e1v = ro[NA + i + 1];
        int na = e0v - b0, nt = e1v - b1;
        int sA = (lane < na) ? (int)csr[b0 + lane] : -1;
        int sT = (lane < nt) ? (int)csr[b1 + lane] : -1;

        float4 accA = make_float4(0.f, 0.f, 0.f, 0.f);
        int ngA = min(na, 64);
        for (int g = 0; g * 8 < ngA; ++g) {
            int s = __shfl(sA, g * 8 + e8, 64);
            if (s >= 0) {
                float w = c_aa[s];
                float4 xv = *(const float4*)(x_a + (size_t)s * 32 + k4 * 4);
                accA.x = fmaf(xv.x, w, accA.x);
                accA.y = fmaf(xv.y, w, accA.y);
                accA.z = fmaf(xv.z, w, accA.z);
                accA.w = fmaf(xv.w, w, accA.w);
            }
        }
        for (int j = b0 + 64 + e8; j < e0v; j += 8) {   // rare tail
            int s = csr[j];
            float w = c_aa[s];
            float4 xv = *(const float4*)(x_a + (size_t)s * 32 + k4 * 4);
            accA.x = fmaf(xv.x, w, accA.x);
            accA.y = fmaf(xv.y, w, accA.y);
            accA.z = fmaf(xv.z, w, accA.z);
            accA.w = fmaf(xv.w, w, accA.w);
        }
        if (e8 == 0) {  // self-loop
            float4 xv = *(const float4*)(x_a + (size_t)i * 32 + k4 * 4);
            accA.x = fmaf(xv.x, ci, accA.x);
            accA.y = fmaf(xv.y, ci, accA.y);
            accA.z = fmaf(xv.z, ci, accA.z);
            accA.w = fmaf(xv.w, ci, accA.w);
        }
        float4 accT = make_float4(0.f, 0.f, 0.f, 0.f);
        int ngT = min(nt, 64);
        for (int g = 0; g * 8 < ngT; ++g) {
            int s = __shfl(sT, g * 8 + e8, 64);
            if (s >= 0) {
                float w = c_ta_s[s];
                float4 xv = *(const float4*)(x_t + (size_t)s * 32 + k4 * 4);
                accT.x = fmaf(xv.x, w, accT.x);
                accT.y = fmaf(xv.y, w, accT.y);
                accT.z = fmaf(xv.z, w, accT.z);
                accT.w = fmaf(xv.w, w, accT.w);
            }
        }
        for (int j = b1 + 64 + e8; j < e1v; j += 8) {   // rare tail
            int s = csr[j];
            float w = c_ta_s[s];
            float4 xv = *(const float4*)(x_t + (size_t)s * 32 + k4 * 4);
            accT.x = fmaf(xv.x, w, accT.x);
            accT.y = fmaf(xv.y, w, accT.y);
            accT.z = fmaf(xv.z, w, accT.z);
            accT.w = fmaf(xv.w, w, accT.w);
        }
#pragma unroll
        for (int m = 8; m <= 32; m <<= 1) {
            accA.x += __shfl_xor(accA.x, m, 64);
            accA.y += __shfl_xor(accA.y, m, 64);
            accA.z += __shfl_xor(accA.z, m, 64);
            accA.w += __shfl_xor(accA.w, m, 64);
            accT.x += __shfl_xor(accT.x, m, 64);
            accT.y += __shfl_xor(accT.y, m, 64);
            accT.z += __shfl_xor(accT.z, m, 64);
            accT.w += __shfl_xor(accT.w, m, 64);
        }
        // wave-coherent LDS publish: lanes 0..7 hold slice k4=lane
        if (lane < 8) {
            *(float4*)&sAggA[wave][lane * 4] = make_float4(accA.x, accA.y, accA.z, accA.w);
            *(float4*)&sAggT[wave][lane * 4] = make_float4(accT.x, accT.y, accT.z, accT.w);
        }
        // matvec: same-address b128 broadcasts (conflict-free), W via pad-33 LDS
        float hA = 0.f, hT = 0.f;
#pragma unroll
        for (int g = 0; g < 8; ++g) {
            float4 aA = *(const float4*)&sAggA[wave][g * 4];
            float4 aT = *(const float4*)&sAggT[wave][g * 4];
            const float* wa = &sW0[lane * 33 + g * 4];
            const float* wt = &sW1[lane * 33 + g * 4];
            hA = fmaf(aA.x, wa[0], hA); hA = fmaf(aA.y, wa[1], hA);
            hA = fmaf(aA.z, wa[2], hA); hA = fmaf(aA.w, wa[3], hA);
            hT = fmaf(aT.x, wt[0], hT); hT = fmaf(aT.y, wt[1], hT);
            hT = fmaf(aT.z, wt[2], hT); hT = fmaf(aT.w, wt[3], hT);
        }
        float h = fmaxf(bias + ci * hA + c_ta_d[i] * hT, 0.f);
        float p0 = h * U[lane * 2], p1 = h * U[lane * 2 + 1];
        float q0 = h * U[256 + lane * 2], q1 = h * U[256 + lane * 2 + 1];
#pragma unroll
        for (int m = 32; m; m >>= 1) {
            p0 += __shfl_xor(p0, m, 64);
            p1 += __shfl_xor(p1, m, 64);
            q0 += __shfl_xor(q0, m, 64);
            q1 += __shfl_xor(q1, m, 64);
        }
        if (lane == 0) {
            float cq = c_at_s[i];
            *(float2*)&p[i * 2] = make_float2(p0 * ci, p1 * ci);
            *(float2*)&q[i * 2] = make_float2(q0 * cq, q1 * cq);
        }
    } else {
        // ---------- targets ----------
        for (int idx = threadIdx.x; idx < 2048; idx += 256) {
            int k = idx >> 6, col = idx & 63;
            sW0[col * 33 + k] = W_at[idx];
        }
        __syncthreads();
        int i = (blockIdx.x - NA / 4) * 4 + wave;
        float bias = b_at[lane];
        int b0 = ro[2 * NA + i], e0v = ro[2 * NA + i + 1];
        int na = e0v - b0;
        int sA = (lane < na) ? (int)csr[b0 + lane] : -1;
        float4 acc = make_float4(0.f, 0.f, 0.f, 0.f);
        int ng = min(na, 64);
        for (int g = 0; g * 8 < ng; ++g) {
            int s = __shfl(sA, g * 8 + e8, 64);
            if (s >= 0) {
                float w = c_at_s[s];
                float4 xv = *(const float4*)(x_a + (size_t)s * 32 + k4 * 4);
                acc.x = fmaf(xv.x, w, acc.x);
                acc.y = fmaf(xv.y, w, acc.y);
                acc.z = fmaf(xv.z, w, acc.z);
                acc.w = fmaf(xv.w, w, acc.w);
            }
        }
        for (int j = b0 + 64 + e8; j < e0v; j += 8) {   // rare tail
            int s = csr[j];
            float w = c_at_s[s];
            float4 xv = *(const float4*)(x_a + (size_t)s * 32 + k4 * 4);
            acc.x = fmaf(xv.x, w, acc.x);
            acc.y = fmaf(xv.y, w, acc.y);
            acc.z = fmaf(xv.z, w, acc.z);
            acc.w = fmaf(xv.w, w, acc.w);
        }
#pragma unroll
        for (int m = 8; m <= 32; m <<= 1) {
            acc.x += __shfl_xor(acc.x, m, 64);
            acc.y += __shfl_xor(acc.y, m, 64);
            acc.z += __shfl_xor(acc.z, m, 64);
            acc.w += __shfl_xor(acc.w, m, 64);
        }
        if (lane < 8)
            *(float4*)&sAggA[wave][lane * 4] = make_float4(acc.x, acc.y, acc.z, acc.w);
        float hA = 0.f;
#pragma unroll
        for (int g = 0; g < 8; ++g) {
            float4 aA = *(const float4*)&sAggA[wave][g * 4];
            const float* wv = &sW0[lane * 33 + g * 4];
            hA = fmaf(aA.x, wv[0], hA); hA = fmaf(aA.y, wv[1], hA);
            hA = fmaf(aA.z, wv[2], hA); hA = fmaf(aA.w, wv[3], hA);
        }
        float h = fmaxf(bias + c_at_d[i] * hA, 0.f);
        float r0 = h * U[128 + lane * 2], r1 = h * U[128 + lane * 2 + 1];
#pragma unroll
        for (int m = 32; m; m >>= 1) {
            r0 += __shfl_xor(r0, m, 64);
            r1 += __shfl_xor(r1, m, 64);
        }
        if (lane == 0) {
            float cr = c_ta_s[i];
            *(float2*)&r[i * 2] = make_float2(r0 * cr, r1 * cr);
        }
    }
}

// ---------- conv2+proj: one wave per node, 32 edge slots x 2 comps ----------
__global__ void __launch_bounds__(256)
out_all_kernel(const float* __restrict__ p, const float* __restrict__ q,
               const float* __restrict__ r, const int* __restrict__ ro,
               const unsigned short* __restrict__ csr,
               const float* __restrict__ c_aa, const float* __restrict__ c_ta_d,
               const float* __restrict__ c_at_d, const float* __restrict__ U,
               float* __restrict__ out) {
    int wgid = blockIdx.x * 4 + (threadIdx.x >> 6);
    int lane = threadIdx.x & 63;
    int slot = lane >> 1, j = lane & 1;
    if (wgid < NA) {
        int i = wgid;
        int b0 = ro[i], n0 = ro[i + 1] - b0;
        float accA = (slot == 0) ? p[i * 2 + j] : 0.f;   // self-loop (p premultiplied)
        for (int e = slot; e < n0; e += 32) accA += p[(int)csr[b0 + e] * 2 + j];
        int b1 = ro[NA + i], n1 = ro[NA + i + 1] - b1;
        float accT = 0.f;
        for (int e = slot; e < n1; e += 32) accT += r[(int)csr[b1 + e] * 2 + j];
#pragma unroll
        for (int m = 2; m <= 32; m <<= 1) {
            accA += __shfl_xor(accA, m, 64);
            accT += __shfl_xor(accT, m, 64);
        }
        if (lane < 2) out[i * 2 + j] = U[384 + j] + accA * c_aa[i] + accT * c_ta_d[i];
    } else {
        int i = wgid - NA;
        int b0 = ro[2 * NA + i], n0 = ro[2 * NA + i + 1] - b0;
        float acc = 0.f;
        for (int e = slot; e < n0; e += 32) acc += q[(int)csr[b0 + e] * 2 + j];
#pragma unroll
        for (int m = 2; m <= 32; m <<= 1) acc += __shfl_xor(acc, m, 64);
        if (lane < 2) out[NA * 2 + i * 2 + j] = U[386 + j] + acc * c_at_d[i];
    }
}

extern "C" void kernel_launch(void* const* d_in, const int* in_sizes, int n_in,
                              void* d_out, int out_size, void* d_ws, size_t ws_size,
                              hipStream_t stream) {
    const float* x_a   = (const float*)d_in[1];
    const float* x_t   = (const float*)d_in[2];
    const int* src_aa  = (const int*)d_in[3];
    const int* dst_aa  = (const int*)d_in[4];
    const int* src_at  = (const int*)d_in[5];
    const int* dst_at  = (const int*)d_in[6];
    const int* src_ta  = (const int*)d_in[7];
    const int* dst_ta  = (const int*)d_in[8];
    const float* W1_aa = (const float*)d_in[9];
    const float* b1_aa = (const float*)d_in[10];
    const float* W1_at = (const float*)d_in[11];
    const float* b1_at = (const float*)d_in[12];
    const float* W1_ta = (const float*)d_in[13];
    const float* b1_ta = (const float*)d_in[14];
    const float* W2_aa = (const float*)d_in[15];
    const float* b2_aa = (const float*)d_in[16];
    const float* W2_at = (const float*)d_in[17];
    const float* b2_at = (const float*)d_in[18];
    const float* W2_ta = (const float*)d_in[19];
    const float* b2_ta = (const float*)d_in[20];
    const float* Wp_a  = (const float*)d_in[21];
    const float* bp_a  = (const float*)d_in[22];
    const float* Wp_t  = (const float*)d_in[23];
    const float* bp_t  = (const float*)d_in[24];

    int*   wi  = (int*)d_ws;
    float* wf  = (float*)d_ws;
    unsigned short* csr = (unsigned short*)(wi + O_CSR);
    float* out = (float*)d_out;

    // single memset: 8-copy src-degree histograms + adjacent bucket totals
    hipMemsetAsync(wi + O_SRCH, 0, (size_t)(8 * SRCH_STRIDE + 512) * 4, stream);

    // fused pass 1: single edge read -> LDS bucket sort -> slab flush (+ src degrees)
    p1_fused_kernel<<<NBLK1, 1024, 0, stream>>>(src_aa, dst_aa, src_ta, dst_ta,
                                                src_at, dst_at, wi);

    // fused pass 2 + aux: p2 (self-computed bases) | src coefs | U fuse
    p2_aux_kernel<<<NB + 75, 1024, 0, stream>>>(wi, wf, W2_aa, W2_ta, W2_at,
                                                b2_aa, b2_ta, b2_at,
                                                Wp_a, bp_a, Wp_t, bp_t);

    // conv1: preload+shfl gather + LDS-broadcast matvec (pad-33, conflict-free)
    conv1_all_kernel<<<NA / 4 + NT / 4, 256, 0, stream>>>(
        x_a, x_t, wi + O_RO, csr,
        wf + O_CAA, wf + O_CTAD, wf + O_CTAS, wf + O_CATS, wf + O_CATD,
        W1_aa, b1_aa, W1_ta, b1_ta, W1_at, b1_at, wf + O_U,
        wf + O_P, wf + O_Q, wf + O_R);

    // conv2 + projection, wave per node
    out_all_kernel<<<(NA + NT) / 4, 256, 0, stream>>>(
        wf + O_P, wf + O_Q, wf + O_R, wi + O_RO, csr,
        wf + O_CAA, wf + O_CTAD, wf + O_CATD, wf + O_U, out);
}

// Round 24
// 253.243 us; speedup vs baseline: 1.0608x; 1.0608x over previous
//
#include <hip/hip_runtime.h>

#define NA 50000
#define NT 25000
#define EAA 800000
#define EAT 400000
#define ETA 400000
#define NSEG 125000          // NA + NA + NT rows: [aa | ta | at]
#define TOTAL_E 1600000
#define NB 489               // coarse buckets of 256 rows
#define NBLK1 391            // pass-1 blocks
#define CHUNK 4096           // edges per pass-1 block
#define CAP 6144             // REC slab capacity per bucket (max observed bucket ~4800)
#define SRCH_STRIDE 75008    // per-copy src-histogram stride: at[50000] | ta[25000] | pad

// ---- workspace layout (4-byte element offsets) ----
#define O_SRCH    0          // int[8*75008]: 8 XCD-local src-degree histogram copies
#define O_BTOT    600064     // int[512]: per-bucket totals (adjacent to SRCH -> single memset)
#define O_RO      600576     // int[125001]: CSR row offsets
#define O_CAA     725584     // float[50000]: rsqrt(indeg_aa+1)
#define O_CTAD    775584     // float[50000]
#define O_CATD    825584     // float[25000]
#define O_CATS    850584     // float[50000]
#define O_CTAS    900584     // float[25000]
#define O_U       925600     // float[512] (padded start)
#define O_P       926112     // float[100000]
#define O_Q       1026112    // float[100000]
#define O_R       1126112    // float[50000]
#define O_REC     1176112    // int[NB*CAP=3004416]: slabbed bucket-sorted records
#define O_CSR     4180528    // ushort[1600000] = 800000 ints

__device__ __forceinline__ float bcast(float v, int l) {
    return __int_as_float(__builtin_amdgcn_readlane(__float_as_int(v), l));
}

// ---------- fused pass 1: load edges once -> LDS bucket sort -> slab flush (+ src degrees) ----------
__global__ void __launch_bounds__(1024)
p1_fused_kernel(const int* __restrict__ src_aa, const int* __restrict__ dst_aa,
                const int* __restrict__ src_ta, const int* __restrict__ dst_ta,
                const int* __restrict__ src_at, const int* __restrict__ dst_at,
                int* __restrict__ wi) {
    __shared__ int recs[CHUNK];              // staged packed (rl<<16)|src
    __shared__ unsigned short bkt[CHUNK];    // bucket per staged edge
    __shared__ int sorted[CHUNK];            // bucket-sorted records
    __shared__ unsigned short sbkt[CHUNK];   // bucket per sorted slot
    __shared__ int cnt[NB];                  // per-bucket count
    __shared__ int cur[NB];                  // scan cursor (ends at offs+cnt)
    __shared__ int gbase[NB];                // scan buffer, then global base - offs
    int b = blockIdx.x, tid = threadIdx.x;
    int* rec_g = wi + O_REC;

    for (int i = tid; i < NB; i += 1024) cnt[i] = 0;
    __syncthreads();

    // phase A: load + stage + count (+ XCD-local src-degree atomics)
    int t0 = b * CHUNK;
    int n = min(CHUNK, TOTAL_E - t0);
    int* srch = wi + O_SRCH + (b & 7) * SRCH_STRIDE;
    for (int i = tid; i < n; i += 1024) {
        int t = t0 + i, row, s;
        if (t < EAA) {
            row = dst_aa[t]; s = src_aa[t];
        } else if (t < EAA + ETA) {
            int u = t - EAA;
            row = NA + dst_ta[u]; s = src_ta[u];
            atomicAdd(&srch[50000 + s], 1);
        } else {
            int u = t - EAA - ETA;
            row = 2 * NA + dst_at[u]; s = src_at[u];
            atomicAdd(&srch[s], 1);
        }
        int bk = row >> 8;
        recs[i] = ((row & 255) << 16) | s;
        bkt[i] = (unsigned short)bk;
        atomicAdd(&cnt[bk], 1);
    }
    __syncthreads();

    // phase B: exclusive scan of cnt -> cur (scan buffer = gbase)
    if (tid < NB) gbase[tid] = cnt[tid];
    __syncthreads();
    for (int off = 1; off < NB; off <<= 1) {
        int x = 0;
        if (tid < NB && tid >= off) x = gbase[tid - off];
        __syncthreads();
        if (tid < NB) gbase[tid] += x;
        __syncthreads();
    }
    if (tid < NB) cur[tid] = gbase[tid] - cnt[tid];   // exclusive offs
    __syncthreads();

    // phase C: place into LDS-sorted order
    for (int i = tid; i < n; i += 1024) {
        int bk = bkt[i];
        int pos = atomicAdd(&cur[bk], 1);
        sorted[pos] = recs[i];
        sbkt[pos] = (unsigned short)bk;
    }
    __syncthreads();

    // phase D: reserve global slab space per bucket; gbase = slab_base - offs
    for (int bk = tid; bk < NB; bk += 1024) {
        int len = cnt[bk];
        if (len > 0) {
            int gb = atomicAdd(&wi[O_BTOT + bk], len);
            gbase[bk] = bk * CAP + gb - (cur[bk] - len);   // cur now = offs+len
        }
    }
    __syncthreads();

    // phase E: flush contiguous runs to the slab
    for (int i = tid; i < n; i += 1024) {
        int bk = sbkt[i];
        rec_g[gbase[bk] + i] = sorted[i];
    }
}

// ---------- fused pass 2 + aux: blocks 0..NB-1 = p2 (self-computed base); NB..NB+73 = src coefs; NB+74 = U ----------
__global__ void __launch_bounds__(1024)
p2_aux_kernel(int* __restrict__ wi, float* __restrict__ wf,
              const float* __restrict__ W2_aa, const float* __restrict__ W2_ta,
              const float* __restrict__ W2_at, const float* __restrict__ b2_aa,
              const float* __restrict__ b2_ta, const float* __restrict__ b2_at,
              const float* __restrict__ Wp_a, const float* __restrict__ bp_a,
              const float* __restrict__ Wp_t, const float* __restrict__ bp_t) {
    int bb = blockIdx.x, tid = threadIdx.x, lane = tid & 63, wid = tid >> 6;
    if (bb < NB) {
        const int* rec = wi + O_REC;
        unsigned short* csr = (unsigned short*)(wi + O_CSR);
        int* ro = wi + O_RO;
        float* caa = wf + O_CAA;
        float* ctad = wf + O_CTAD;
        float* catd = wf + O_CATD;
        __shared__ int deg[256];
        __shared__ int rb[256];
        __shared__ int wsum[16];
        int k = bb;
        // self-compute g0 = sum of BTOT[0..k)
        int a = (tid < k) ? wi[O_BTOT + tid] : 0;
#pragma unroll
        for (int m = 32; m; m >>= 1) a += __shfl_xor(a, m, 64);
        if (lane == 0) wsum[wid] = a;
        if (tid < 256) deg[tid] = 0;
        __syncthreads();
        int g0 = 0;
#pragma unroll
        for (int w = 0; w < 16; ++w) g0 += wsum[w];
        int s0 = k * CAP;                       // slab base
        int len = wi[O_BTOT + k];
        for (int j = tid; j < len; j += 1024) atomicAdd(&deg[rec[s0 + j] >> 16], 1);
        __syncthreads();
        int v = 0, x = 0;
        if (tid < 256) {
            v = deg[tid];
            x = v;
#pragma unroll
            for (int off = 1; off < 64; off <<= 1) {
                int y = __shfl_up(x, off, 64);
                if (lane >= off) x += y;
            }
            if (lane == 63) wsum[wid] = x;
        }
        __syncthreads();
        if (tid < 256) {
            int wpre = 0;
            for (int w = 0; w < wid; ++w) wpre += wsum[w];
            int excl = x - v + wpre;
            rb[tid] = g0 + excl;
            int g = k * 256 + tid;
            if (g < NSEG) {
                ro[g] = g0 + excl;
                if (g < NA) caa[g] = rsqrtf((float)v + 1.0f);
                else if (g < 2 * NA) ctad[g - NA] = v > 0 ? rsqrtf((float)v) : 0.0f;
                else catd[g - 2 * NA] = v > 0 ? rsqrtf((float)v) : 0.0f;
            }
            if (k == NB - 1 && tid == 0) ro[NSEG] = TOTAL_E;
        }
        __syncthreads();
        for (int j = tid; j < len; j += 1024) {
            int rc = rec[s0 + j];
            int pos = atomicAdd(&rb[rc >> 16], 1);
            csr[pos] = (unsigned short)(rc & 0xFFFF);
        }
    } else if (bb < NB + 74) {
        int t = (bb - NB) * 1024 + tid;
        if (t < 75000) {
            int d = 0;
#pragma unroll
            for (int c = 0; c < 8; ++c) d += wi[O_SRCH + c * SRCH_STRIDE + t];
            float v = d > 0 ? rsqrtf((float)d) : 0.0f;
            if (t < 50000) wf[O_CATS + t] = v;
            else           wf[O_CTAS + (t - 50000)] = v;
        }
    } else {
        float* U = wf + O_U;
        int t = tid;
        if (t < 128) {
            int k = t >> 1, j = t & 1;
            float a = 0.f;
            for (int f = 0; f < 64; ++f) a = fmaf(W2_aa[k * 64 + f], Wp_a[f * 2 + j], a);
            U[t] = a;
        } else if (t < 256) {
            int u = t - 128; int k = u >> 1, j = u & 1;
            float a = 0.f;
            for (int f = 0; f < 64; ++f) a = fmaf(W2_ta[k * 64 + f], Wp_a[f * 2 + j], a);
            U[128 + u] = a;
        } else if (t < 384) {
            int u = t - 256; int k = u >> 1, j = u & 1;
            float a = 0.f;
            for (int f = 0; f < 64; ++f) a = fmaf(W2_at[k * 64 + f], Wp_t[f * 2 + j], a);
            U[256 + u] = a;
        } else if (t < 386) {
            int j = t - 384;
            float a = bp_a[j];
            for (int f = 0; f < 64; ++f) a = fmaf(b2_aa[f] + b2_ta[f], Wp_a[f * 2 + j], a);
            U[384 + j] = a;
        } else if (t < 388) {
            int j = t - 386;
            float a = bp_t[j];
            for (int f = 0; f < 64; ++f) a = fmaf(b2_at[f], Wp_t[f * 2 + j], a);
            U[386 + j] = a;
        }
    }
}

// ---------- conv1: preload+shfl gather + readlane-broadcast matvec (pad-33 W in LDS) ----------
__global__ void __launch_bounds__(256)
conv1_all_kernel(const float* __restrict__ x_a, const float* __restrict__ x_t,
                 const int* __restrict__ ro, const unsigned short* __restrict__ csr,
                 const float* __restrict__ c_aa, const float* __restrict__ c_ta_d,
                 const float* __restrict__ c_ta_s, const float* __restrict__ c_at_s,
                 const float* __restrict__ c_at_d,
                 const float* __restrict__ W_aa, const float* __restrict__ b_aa,
                 const float* __restrict__ W_ta, const float* __restrict__ b_ta,
                 const float* __restrict__ W_at, const float* __restrict__ b_at,
                 const float* __restrict__ U,
                 float* __restrict__ p, float* __restrict__ q, float* __restrict__ r) {
    __shared__ float sW0[64 * 33];   // transposed: sW0[col*33 + k], stride 33 -> 2-way banks (free)
    __shared__ float sW1[64 * 33];
    int lane = threadIdx.x & 63;
    int wave = threadIdx.x >> 6;
    int e8 = lane >> 3, k4 = lane & 7;

    if (blockIdx.x < NA / 4) {
        // ---------- agents ----------
        for (int idx = threadIdx.x; idx < 2048; idx += 256) {
            int k = idx >> 6, col = idx & 63;
            sW0[col * 33 + k] = W_aa[idx];
            sW1[col * 33 + k] = W_ta[idx];
        }
        __syncthreads();
        int i = blockIdx.x * 4 + wave;
        float ci = c_aa[i];
        float bias = b_aa[lane] + b_ta[lane];
        int b0 = ro[i], e0v = ro[i + 1];
        int b1 = ro[NA + i], e1v = ro[NA + i + 1];
        int na = e0v - b0, nt = e1v - b1;
        int sA = (lane < na) ? (int)csr[b0 + lane] : -1;
        int sT = (lane < nt) ? (int)csr[b1 + lane] : -1;

        float4 accA = make_float4(0.f, 0.f, 0.f, 0.f);
        int ngA = min(na, 64);
        for (int g = 0; g * 8 < ngA; ++g) {
            int s = __shfl(sA, g * 8 + e8, 64);
            if (s >= 0) {
                float w = c_aa[s];
                float4 xv = *(const float4*)(x_a + (size_t)s * 32 + k4 * 4);
                accA.x = fmaf(xv.x, w, accA.x);
                accA.y = fmaf(xv.y, w, accA.y);
                accA.z = fmaf(xv.z, w, accA.z);
                accA.w = fmaf(xv.w, w, accA.w);
            }
        }
        for (int j = b0 + 64 + e8; j < e0v; j += 8) {   // rare tail
            int s = csr[j];
            float w = c_aa[s];
            float4 xv = *(const float4*)(x_a + (size_t)s * 32 + k4 * 4);
            accA.x = fmaf(xv.x, w, accA.x);
            accA.y = fmaf(xv.y, w, accA.y);
            accA.z = fmaf(xv.z, w, accA.z);
            accA.w = fmaf(xv.w, w, accA.w);
        }
        if (e8 == 0) {  // self-loop
            float4 xv = *(const float4*)(x_a + (size_t)i * 32 + k4 * 4);
            accA.x = fmaf(xv.x, ci, accA.x);
            accA.y = fmaf(xv.y, ci, accA.y);
            accA.z = fmaf(xv.z, ci, accA.z);
            accA.w = fmaf(xv.w, ci, accA.w);
        }
        float4 accT = make_float4(0.f, 0.f, 0.f, 0.f);
        int ngT = min(nt, 64);
        for (int g = 0; g * 8 < ngT; ++g) {
            int s = __shfl(sT, g * 8 + e8, 64);
            if (s >= 0) {
                float w = c_ta_s[s];
                float4 xv = *(const float4*)(x_t + (size_t)s * 32 + k4 * 4);
                accT.x = fmaf(xv.x, w, accT.x);
                accT.y = fmaf(xv.y, w, accT.y);
                accT.z = fmaf(xv.z, w, accT.z);
                accT.w = fmaf(xv.w, w, accT.w);
            }
        }
        for (int j = b1 + 64 + e8; j < e1v; j += 8) {   // rare tail
            int s = csr[j];
            float w = c_ta_s[s];
            float4 xv = *(const float4*)(x_t + (size_t)s * 32 + k4 * 4);
            accT.x = fmaf(xv.x, w, accT.x);
            accT.y = fmaf(xv.y, w, accT.y);
            accT.z = fmaf(xv.z, w, accT.z);
            accT.w = fmaf(xv.w, w, accT.w);
        }
#pragma unroll
        for (int m = 8; m <= 32; m <<= 1) {
            accA.x += __shfl_xor(accA.x, m, 64);
            accA.y += __shfl_xor(accA.y, m, 64);
            accA.z += __shfl_xor(accA.z, m, 64);
            accA.w += __shfl_xor(accA.w, m, 64);
            accT.x += __shfl_xor(accT.x, m, 64);
            accT.y += __shfl_xor(accT.y, m, 64);
            accT.z += __shfl_xor(accT.z, m, 64);
            accT.w += __shfl_xor(accT.w, m, 64);
        }
        float hA = 0.f, hT = 0.f;
#pragma unroll
        for (int g = 0; g < 8; ++g) {
            float a0 = bcast(accA.x, g), a1 = bcast(accA.y, g);
            float a2 = bcast(accA.z, g), a3 = bcast(accA.w, g);
            float t0 = bcast(accT.x, g), t1 = bcast(accT.y, g);
            float t2 = bcast(accT.z, g), t3 = bcast(accT.w, g);
            const float* wa = &sW0[lane * 33 + g * 4];
            const float* wt = &sW1[lane * 33 + g * 4];
            hA = fmaf(a0, wa[0], hA); hA = fmaf(a1, wa[1], hA);
            hA = fmaf(a2, wa[2], hA); hA = fmaf(a3, wa[3], hA);
            hT = fmaf(t0, wt[0], hT); hT = fmaf(t1, wt[1], hT);
            hT = fmaf(t2, wt[2], hT); hT = fmaf(t3, wt[3], hT);
        }
        float h = fmaxf(bias + ci * hA + c_ta_d[i] * hT, 0.f);
        float p0 = h * U[lane * 2], p1 = h * U[lane * 2 + 1];
        float q0 = h * U[256 + lane * 2], q1 = h * U[256 + lane * 2 + 1];
#pragma unroll
        for (int m = 32; m; m >>= 1) {
            p0 += __shfl_xor(p0, m, 64);
            p1 += __shfl_xor(p1, m, 64);
            q0 += __shfl_xor(q0, m, 64);
            q1 += __shfl_xor(q1, m, 64);
        }
        if (lane == 0) {
            float cq = c_at_s[i];
            *(float2*)&p[i * 2] = make_float2(p0 * ci, p1 * ci);
            *(float2*)&q[i * 2] = make_float2(q0 * cq, q1 * cq);
        }
    } else {
        // ---------- targets ----------
        for (int idx = threadIdx.x; idx < 2048; idx += 256) {
            int k = idx >> 6, col = idx & 63;
            sW0[col * 33 + k] = W_at[idx];
        }
        __syncthreads();
        int i = (blockIdx.x - NA / 4) * 4 + wave;
        float bias = b_at[lane];
        int b0 = ro[2 * NA + i], e0v = ro[2 * NA + i + 1];
        int na = e0v - b0;
        int sA = (lane < na) ? (int)csr[b0 + lane] : -1;
        float4 acc = make_float4(0.f, 0.f, 0.f, 0.f);
        int ng = min(na, 64);
        for (int g = 0; g * 8 < ng; ++g) {
            int s = __shfl(sA, g * 8 + e8, 64);
            if (s >= 0) {
                float w = c_at_s[s];
                float4 xv = *(const float4*)(x_a + (size_t)s * 32 + k4 * 4);
                acc.x = fmaf(xv.x, w, acc.x);
                acc.y = fmaf(xv.y, w, acc.y);
                acc.z = fmaf(xv.z, w, acc.z);
                acc.w = fmaf(xv.w, w, acc.w);
            }
        }
        for (int j = b0 + 64 + e8; j < e0v; j += 8) {   // rare tail
            int s = csr[j];
            float w = c_at_s[s];
            float4 xv = *(const float4*)(x_a + (size_t)s * 32 + k4 * 4);
            acc.x = fmaf(xv.x, w, acc.x);
            acc.y = fmaf(xv.y, w, acc.y);
            acc.z = fmaf(xv.z, w, acc.z);
            acc.w = fmaf(xv.w, w, acc.w);
        }
#pragma unroll
        for (int m = 8; m <= 32; m <<= 1) {
            acc.x += __shfl_xor(acc.x, m, 64);
            acc.y += __shfl_xor(acc.y, m, 64);
            acc.z += __shfl_xor(acc.z, m, 64);
            acc.w += __shfl_xor(acc.w, m, 64);
        }
        float hA = 0.f;
#pragma unroll
        for (int g = 0; g < 8; ++g) {
            float a0 = bcast(acc.x, g), a1 = bcast(acc.y, g);
            float a2 = bcast(acc.z, g), a3 = bcast(acc.w, g);
            const float* wv = &sW0[lane * 33 + g * 4];
            hA = fmaf(a0, wv[0], hA); hA = fmaf(a1, wv[1], hA);
            hA = fmaf(a2, wv[2], hA); hA = fmaf(a3, wv[3], hA);
        }
        float h = fmaxf(bias + c_at_d[i] * hA, 0.f);
        float r0 = h * U[128 + lane * 2], r1 = h * U[128 + lane * 2 + 1];
#pragma unroll
        for (int m = 32; m; m >>= 1) {
            r0 += __shfl_xor(r0, m, 64);
            r1 += __shfl_xor(r1, m, 64);
        }
        if (lane == 0) {
            float cr = c_ta_s[i];
            *(float2*)&r[i * 2] = make_float2(r0 * cr, r1 * cr);
        }
    }
}

// ---------- conv2+proj: one wave per node, 32 edge slots x 2 comps ----------
__global__ void __launch_bounds__(256)
out_all_kernel(const float* __restrict__ p, const float* __restrict__ q,
               const float* __restrict__ r, const int* __restrict__ ro,
               const unsigned short* __restrict__ csr,
               const float* __restrict__ c_aa, const float* __restrict__ c_ta_d,
               const float* __restrict__ c_at_d, const float* __restrict__ U,
               float* __restrict__ out) {
    int wgid = blockIdx.x * 4 + (threadIdx.x >> 6);
    int lane = threadIdx.x & 63;
    int slot = lane >> 1, j = lane & 1;
    if (wgid < NA) {
        int i = wgid;
        int b0 = ro[i], n0 = ro[i + 1] - b0;
        float accA = (slot == 0) ? p[i * 2 + j] : 0.f;   // self-loop (p premultiplied)
        for (int e = slot; e < n0; e += 32) accA += p[(int)csr[b0 + e] * 2 + j];
        int b1 = ro[NA + i], n1 = ro[NA + i + 1] - b1;
        float accT = 0.f;
        for (int e = slot; e < n1; e += 32) accT += r[(int)csr[b1 + e] * 2 + j];
#pragma unroll
        for (int m = 2; m <= 32; m <<= 1) {
            accA += __shfl_xor(accA, m, 64);
            accT += __shfl_xor(accT, m, 64);
        }
        if (lane < 2) out[i * 2 + j] = U[384 + j] + accA * c_aa[i] + accT * c_ta_d[i];
    } else {
        int i = wgid - NA;
        int b0 = ro[2 * NA + i], n0 = ro[2 * NA + i + 1] - b0;
        float acc = 0.f;
        for (int e = slot; e < n0; e += 32) acc += q[(int)csr[b0 + e] * 2 + j];
#pragma unroll
        for (int m = 2; m <= 32; m <<= 1) acc += __shfl_xor(acc, m, 64);
        if (lane < 2) out[NA * 2 + i * 2 + j] = U[386 + j] + acc * c_at_d[i];
    }
}

extern "C" void kernel_launch(void* const* d_in, const int* in_sizes, int n_in,
                              void* d_out, int out_size, void* d_ws, size_t ws_size,
                              hipStream_t stream) {
    const float* x_a   = (const float*)d_in[1];
    const float* x_t   = (const float*)d_in[2];
    const int* src_aa  = (const int*)d_in[3];
    const int* dst_aa  = (const int*)d_in[4];
    const int* src_at  = (const int*)d_in[5];
    const int* dst_at  = (const int*)d_in[6];
    const int* src_ta  = (const int*)d_in[7];
    const int* dst_ta  = (const int*)d_in[8];
    const float* W1_aa = (const float*)d_in[9];
    const float* b1_aa = (const float*)d_in[10];
    const float* W1_at = (const float*)d_in[11];
    const float* b1_at = (const float*)d_in[12];
    const float* W1_ta = (const float*)d_in[13];
    const float* b1_ta = (const float*)d_in[14];
    const float* W2_aa = (const float*)d_in[15];
    const float* b2_aa = (const float*)d_in[16];
    const float* W2_at = (const float*)d_in[17];
    const float* b2_at = (const float*)d_in[18];
    const float* W2_ta = (const float*)d_in[19];
    const float* b2_ta = (const float*)d_in[20];
    const float* Wp_a  = (const float*)d_in[21];
    const float* bp_a  = (const float*)d_in[22];
    const float* Wp_t  = (const float*)d_in[23];
    const float* bp_t  = (const float*)d_in[24];

    int*   wi  = (int*)d_ws;
    float* wf  = (float*)d_ws;
    unsigned short* csr = (unsigned short*)(wi + O_CSR);
    float* out = (float*)d_out;

    // single memset: 8-copy src-degree histograms + adjacent bucket totals
    hipMemsetAsync(wi + O_SRCH, 0, (size_t)(8 * SRCH_STRIDE + 512) * 4, stream);

    // fused pass 1: single edge read -> LDS bucket sort -> slab flush (+ src degrees)
    p1_fused_kernel<<<NBLK1, 1024, 0, stream>>>(src_aa, dst_aa, src_ta, dst_ta,
                                                src_at, dst_at, wi);

    // fused pass 2 + aux: p2 (self-computed bases) | src coefs | U fuse
    p2_aux_kernel<<<NB + 75, 1024, 0, stream>>>(wi, wf, W2_aa, W2_ta, W2_at,
                                                b2_aa, b2_ta, b2_at,
                                                Wp_a, bp_a, Wp_t, bp_t);

    // conv1: preload+shfl gather + readlane matvec (pad-33, conflict-free)
    conv1_all_kernel<<<NA / 4 + NT / 4, 256, 0, stream>>>(
        x_a, x_t, wi + O_RO, csr,
        wf + O_CAA, wf + O_CTAD, wf + O_CTAS, wf + O_CATS, wf + O_CATD,
        W1_aa, b1_aa, W1_ta, b1_ta, W1_at, b1_at, wf + O_U,
        wf + O_P, wf + O_Q, wf + O_R);

    // conv2 + projection, wave per node
    out_all_kernel<<<(NA + NT) / 4, 256, 0, stream>>>(
        wf + O_P, wf + O_Q, wf + O_R, wi + O_RO, csr,
        wf + O_CAA, wf + O_CTAD, wf + O_CATD, wf + O_U, out);
}